// Round 10
// baseline (192.985 us; speedup 1.0000x reference)
//
#include <hip/hip_runtime.h>

// Blockwise 16x16 2D DCT (out = K @ T @ K^T), fp32, memory-bound.
// R10: fully wave-local, BARRIER-FREE. One wave owns a 16x256 strip:
//   - 16 x 1KB contiguous global loads: lane l receives cols 4l..4l+3
//     == quarter-columns of tile l>>2 directly in registers.
//   - pass 1 (column DCTs) lane-local in registers, no LDS, no barrier.
//   - one wave-local LDS transpose; ALL accesses at b128 bank floor
//     (tile stride 260 = 4 mod 32; writes buffered into b128 row-segments).
//   - restage to row layout (aliases U; same-wave LDS pipe is in-order).
//   - 16 x 1KB contiguous stores.
// 1024 blocks x 128 thr (2 independent waves), 33KB LDS -> 4 blocks/CU,
// 8 decorrelated waves/CU, 12 strips/wave, exact cover, zero sync.

#define IMG_W   1024
#define TSTRIDE 260        // dwords: 260 % 32 == 4 (bank spread), 1040B % 16 == 0
#define LDSW    4160       // per-wave floats: 16 tiles * 260 == 16 stage rows * 260

typedef float floatx4 __attribute__((ext_vector_type(4)));

// u[i] = sum_j K[i][j]*t[j] via even/odd symmetry of the DCT-II matrix:
// 96 fma + 24 add, kern reads are contiguous row prefixes (s_load friendly).
__device__ __forceinline__ void dct16_fast(const float t[16],
                                           const float* __restrict__ kern,
                                           float u[16]) {
    float s[8], d[8];
    #pragma unroll
    for (int n = 0; n < 8; ++n) { s[n] = t[n] + t[15 - n]; d[n] = t[n] - t[15 - n]; }
    float ss[4], sd[4];
    #pragma unroll
    for (int n = 0; n < 4; ++n) { ss[n] = s[n] + s[7 - n]; sd[n] = s[n] - s[7 - n]; }
    #pragma unroll
    for (int k = 0; k < 4; ++k) {
        float a = 0.0f, b = 0.0f;
        #pragma unroll
        for (int n = 0; n < 4; ++n) {
            a = fmaf(kern[(4 * k) * 16 + n],     ss[n], a);
            b = fmaf(kern[(4 * k + 2) * 16 + n], sd[n], b);
        }
        u[4 * k] = a; u[4 * k + 2] = b;
    }
    #pragma unroll
    for (int k = 0; k < 8; ++k) {
        float a = 0.0f;
        #pragma unroll
        for (int n = 0; n < 8; ++n)
            a = fmaf(kern[(2 * k + 1) * 16 + n], d[n], a);
        u[2 * k + 1] = a;
    }
}

__global__ __launch_bounds__(128) void dct16_kernel(
    const float* __restrict__ x,
    const float* __restrict__ kern,      // 16x16 DCT matrix, row-major
    float* __restrict__ out,
    int strips_per_wave, int total_strips)
{
    __shared__ float lds[2 * LDSW];      // 33280 B -> 4 blocks/CU

    const int tid  = threadIdx.x;        // 0..127
    const int lane = tid & 63;
    const int wid  = tid >> 6;
    float* U = &lds[wid * LDSW];         // wave-private region

    const int t = lane >> 2;             // tile 0..15
    const int q = lane & 3;              // quarter 0..3

    const int gw = blockIdx.x * 2 + wid;
    int s0 = gw * strips_per_wave;
    if (s0 >= total_strips) return;      // no barriers -> early return safe
    int ns = strips_per_wave;
    if (s0 + ns > total_strips) ns = total_strips - s0;

    for (int k = 0; k < ns; ++k) {
        const int s = s0 + k;
        // strip s: 16 rows x 256 cols; band s>>2, quarter s&3
        const size_t base = (size_t)(s >> 2) * (16 * IMG_W) + (size_t)(s & 3) * 256;

        // ---- load: 16 x 1KB contiguous; lane l -> cols 4l..4l+3, all rows ----
        const float* gp = x + base + lane * 4;
        floatx4 T[16];
        #pragma unroll
        for (int r = 0; r < 16; ++r)
            T[r] = *reinterpret_cast<const floatx4*>(gp + (size_t)r * IMG_W);

        // ---- pass 1: 4 lane-local column DCTs (cols 4q+j of tile t) ----
        float u4[4][16];
        #pragma unroll
        for (int j = 0; j < 4; ++j) {
            float tv[16];
            #pragma unroll
            for (int r = 0; r < 16; ++r) tv[r] = T[r][j];
            dct16_fast(tv, kern, u4[j]);
        }

        // ---- U write: b128 row-segments, banks at floor ----
        // U layout: [tile][row*16 + col], tile stride 260
        {
            float* Ub = &U[t * TSTRIDE + 4 * q];
            #pragma unroll
            for (int r = 0; r < 16; ++r) {
                floatx4 v = { u4[0][r], u4[1][r], u4[2][r], u4[3][r] };
                *reinterpret_cast<floatx4*>(Ub + r * 16) = v;
            }
        }

        // ---- pass 2: rows R = q+4rr of tile t (b128 reads, banks at floor) ----
        float od[4][16];
        #pragma unroll
        for (int rr = 0; rr < 4; ++rr) {
            const int R = q + 4 * rr;
            const float* Ur = &U[t * TSTRIDE + R * 16];
            float rv[16];
            #pragma unroll
            for (int p = 0; p < 4; ++p) {
                floatx4 v = *reinterpret_cast<const floatx4*>(Ur + 4 * p);
                rv[4*p+0] = v.x; rv[4*p+1] = v.y; rv[4*p+2] = v.z; rv[4*p+3] = v.w;
            }
            dct16_fast(rv, kern, od[rr]);
        }

        // ---- restage to row-major [strip_row][260] (aliases U; all U reads
        //      precede these writes in program order; same-wave LDS is in-order)
        #pragma unroll
        for (int rr = 0; rr < 4; ++rr) {
            const int R = q + 4 * rr;
            float* st = &U[R * TSTRIDE + t * 16];
            #pragma unroll
            for (int f = 0; f < 4; ++f) {
                floatx4 v = { od[rr][4*f+0], od[rr][4*f+1], od[rr][4*f+2], od[rr][4*f+3] };
                *reinterpret_cast<floatx4*>(st + 4 * f) = v;
            }
        }

        // ---- store: 16 x 1KB contiguous (b128 stage reads are contiguous) ----
        float* gout = out + base + lane * 4;
        #pragma unroll
        for (int r = 0; r < 16; ++r) {
            floatx4 v = *reinterpret_cast<const floatx4*>(&U[r * TSTRIDE + lane * 4]);
            *reinterpret_cast<floatx4*>(gout + (size_t)r * IMG_W) = v;
        }
    }
}

extern "C" void kernel_launch(void* const* d_in, const int* in_sizes, int n_in,
                              void* d_out, int out_size, void* d_ws, size_t ws_size,
                              hipStream_t stream) {
    const float* x    = (const float*)d_in[0];
    const float* kern = (const float*)d_in[1];
    float* out        = (float*)d_out;

    const int n_img        = in_sizes[0] / (IMG_W * IMG_W);   // 96
    const int total_strips = n_img * 256;                     // 24576 strips of 16x256
    const int blocks       = 1024;                            // 4 resident/CU (LDS)
    const int n_waves      = blocks * 2;                      // 2048 independent waves
    const int per_wave     = (total_strips + n_waves - 1) / n_waves;  // 12, exact

    dct16_kernel<<<blocks, 128, 0, stream>>>(x, kern, out, per_wave, total_strips);
}

// Round 12
// 192.027 us; speedup vs baseline: 1.0050x; 1.0050x over previous
//
#include <hip/hip_runtime.h>

// Blockwise 16x16 2D DCT (out = K @ T @ K^T), fp32.
// R11 = R7 skeleton (best: 168us) minus output staging:
//  - pass-2 threads store their 64B-contiguous output row DIRECTly to global
//    (4x16B; L2 write-back merges full lines -> no partial-line HBM cost).
//  - deletes 8 b128 LDS instrs + tail addressing per thread (~10% of VALU).
//  - write_strip(k+1)/load_strip(k+2) moved between B_mid and pass 2.
//  - register prefetch, fast symmetric DCT, 2 barriers/iter, 4 blocks/CU kept.
// 1024 persistent blocks x 256 thr, 24 strips of 16x256 each.

#define IMG_W  1024
#define SCOLS  256
#define U0     4096         // U region starts after ibuf
#define UTILE  336          // per-tile: 16*20 + 16 slack (bank rotation)
#define USTR   20           // U row stride (80B, 16B-aligned)
#define LDS_FLOATS 9472     // 4096 + 16*336 = 37888 B -> 4 blocks/CU

typedef float floatx4 __attribute__((ext_vector_type(4)));

// u[i] = sum_j K[i][j]*t[j] via even/odd symmetry of the DCT-II matrix:
// 96 fma + 24 add, kern reads are contiguous row prefixes (s_load friendly).
__device__ __forceinline__ void dct16_fast(const float t[16],
                                           const float* __restrict__ kern,
                                           float u[16]) {
    float s[8], d[8];
    #pragma unroll
    for (int n = 0; n < 8; ++n) { s[n] = t[n] + t[15 - n]; d[n] = t[n] - t[15 - n]; }
    float ss[4], sd[4];
    #pragma unroll
    for (int n = 0; n < 4; ++n) { ss[n] = s[n] + s[7 - n]; sd[n] = s[n] - s[7 - n]; }
    #pragma unroll
    for (int k = 0; k < 4; ++k) {
        float a = 0.0f, b = 0.0f;
        #pragma unroll
        for (int n = 0; n < 4; ++n) {
            a = fmaf(kern[(4 * k) * 16 + n],     ss[n], a);
            b = fmaf(kern[(4 * k + 2) * 16 + n], sd[n], b);
        }
        u[4 * k] = a; u[4 * k + 2] = b;
    }
    #pragma unroll
    for (int k = 0; k < 8; ++k) {
        float a = 0.0f;
        #pragma unroll
        for (int n = 0; n < 8; ++n)
            a = fmaf(kern[(2 * k + 1) * 16 + n], d[n], a);
        u[2 * k + 1] = a;
    }
}

__global__ __launch_bounds__(256, 4) void dct16_kernel(
    const float* __restrict__ x,
    const float* __restrict__ kern,      // 16x16 DCT matrix, row-major
    float* __restrict__ out,
    int strips_per_block, int total_strips)
{
    __shared__ float lds[LDS_FLOATS];

    const int tid  = threadIdx.x;
    const int lane = tid & 63;
    const int wid  = tid >> 6;

    int s0 = blockIdx.x * strips_per_block;
    if (s0 >= total_strips) return;                 // uniform per block
    int ns = strips_per_block;
    if (s0 + ns > total_strips) ns = total_strips - s0;

    // strip s: 16 rows x 256 cols. band = s>>2, quarter = s&3.
    auto sbase = [](int s) -> size_t {
        return (size_t)(s >> 2) * (16 * IMG_W) + (size_t)(s & 3) * SCOLS;
    };

    floatx4 pre[4];                                 // prefetch regs (one strip)

    // load strip s into regs: instr f = row 4*wid+f, 1KB contiguous per instr
    auto load_strip = [&](int s) {
        const float* g = x + sbase(s) + (size_t)(4 * wid) * IMG_W + lane * 4;
        #pragma unroll
        for (int f = 0; f < 4; ++f)
            pre[f] = *reinterpret_cast<const floatx4*>(g + (size_t)f * IMG_W);
    };
    // regs -> ibuf (compiler inserts the counted vmcnt before first use of pre)
    auto write_strip = [&]() {
        #pragma unroll
        for (int f = 0; f < 4; ++f)
            *reinterpret_cast<floatx4*>(&lds[(4 * wid + f) * SCOLS + lane * 4]) = pre[f];
    };

    // prologue: strip s0 regs -> ibuf; prefetch s0+1
    load_strip(s0);
    write_strip();
    if (ns > 1) load_strip(s0 + 1);

    for (int k = 0; k < ns; ++k) {
        asm volatile("s_waitcnt lgkmcnt(0)" ::: "memory");
        __builtin_amdgcn_s_barrier();               // B_top: ibuf = strip k
        asm volatile("" ::: "memory");

        // ---- Pass 1: U = K @ T. Thread = column c = tid. ----
        {
            const int t  = tid >> 4;
            const int cl = tid & 15;
            float tv[16];
            #pragma unroll
            for (int j = 0; j < 16; ++j) tv[j] = lds[j * SCOLS + tid];

            float u[16];
            dct16_fast(tv, kern, u);

            float* U = &lds[U0 + t * UTILE];
            #pragma unroll
            for (int i = 0; i < 16; ++i)
                U[i * USTR + cl] = u[i];
        }
        asm volatile("s_waitcnt lgkmcnt(0)" ::: "memory");
        __builtin_amdgcn_s_barrier();               // B_mid: all ibuf reads done
        asm volatile("" ::: "memory");

        // ---- refill ibuf for k+1, issue loads for k+2 (1.5 iters of slack) ----
        if (k + 1 < ns) write_strip();
        if (k + 2 < ns) load_strip(s0 + k + 2);

        // ---- Pass 2: O = U @ K^T. Thread = (tile t, row r). Wave-local U. ----
        {
            const int t = tid >> 4;
            const int r = tid & 15;
            const float* Ur = &lds[U0 + t * UTILE + r * USTR];

            float ur[16];
            #pragma unroll
            for (int p = 0; p < 4; ++p) {
                floatx4 v = *reinterpret_cast<const floatx4*>(Ur + p * 4);
                ur[p*4+0] = v.x; ur[p*4+1] = v.y; ur[p*4+2] = v.z; ur[p*4+3] = v.w;
            }

            float o[16];
            dct16_fast(ur, kern, o);

            // direct store: thread owns 64B-contiguous run (row r, cols 16t..16t+15)
            float* g = out + sbase(s0 + k) + (size_t)r * IMG_W + t * 16;
            #pragma unroll
            for (int f = 0; f < 4; ++f) {
                floatx4 v = { o[4*f+0], o[4*f+1], o[4*f+2], o[4*f+3] };
                *reinterpret_cast<floatx4*>(g + 4 * f) = v;
            }
        }
    }
}

extern "C" void kernel_launch(void* const* d_in, const int* in_sizes, int n_in,
                              void* d_out, int out_size, void* d_ws, size_t ws_size,
                              hipStream_t stream) {
    const float* x    = (const float*)d_in[0];
    const float* kern = (const float*)d_in[1];
    float* out        = (float*)d_out;

    const int n_img        = in_sizes[0] / (IMG_W * IMG_W);   // 96
    const int total_strips = n_img * 256;                     // 24576
    const int blocks       = 1024;                            // 4 per CU
    const int per_block    = (total_strips + blocks - 1) / blocks;  // 24, exact

    dct16_kernel<<<blocks, 256, 0, stream>>>(x, kern, out, per_block, total_strips);
}

// Round 13
// 167.168 us; speedup vs baseline: 1.1544x; 1.1487x over previous
//
#include <hip/hip_runtime.h>
#include <hip/hip_bf16.h>

// Blockwise 16x16 2D DCT (out = K @ T @ K^T), fp32 in/out, bf16 MFMA compute.
// R13: replace 240 scalar FMA/thread with 2x v_mfma_f32_16x16x16_bf16 per tile.
//  - V = T*K^T (MFMA1), O = K*V (MFMA2).  Layouts (ISA Sec.10 + m162 tr-read):
//    A[i][k]: i=lane&15, k=4g+j;  B[k][c]: c=lane&15, k=4g+j;  D: row=4g+r.
//    => D1 regs (V rows 4g+r) ARE B2's elements (k=4g+j): lane-local handoff,
//    no shuffles, no input LDS. One constant K-frag serves B1(=K^T) and A2(=K).
//  - per tile: 1 global b128 load (16B/lane, 16 full 64B lines/instr),
//    4 cvt-pk, 2 MFMA, 4 stage b32 writes.
//  - staged 1KB-row stores (R7-proven; R11 direct stores regressed).
// 1024 blocks x 256 thr (4 waves; wave w = tiles 4w..4w+3), 24 strips each.

#define IMG_W 1024
#define SSTR  260            // stage row stride (dwords): 260%32=4, 16B-aligned
#define LDS_FLOATS 4160      // 16 rows x 260 = 16640 B

typedef float floatx4 __attribute__((ext_vector_type(4)));
typedef int   intx2   __attribute__((ext_vector_type(2)));

__device__ __forceinline__ int pk2(float a, float b) {
    __hip_bfloat16 ha = __float2bfloat16(a);
    __hip_bfloat16 hb = __float2bfloat16(b);
    unsigned short ua, ub;
    __builtin_memcpy(&ua, &ha, 2);
    __builtin_memcpy(&ub, &hb, 2);
    return (int)((unsigned)ua | ((unsigned)ub << 16));
}

#define MFMA16(D, A, B, C)                                        \
    asm volatile("v_mfma_f32_16x16x16_bf16 %0, %1, %2, %3"        \
                 : "=&v"(D) : "v"(A), "v"(B), "v"(C))

__global__ __launch_bounds__(256, 4) void dct16_kernel(
    const float* __restrict__ x,
    const float* __restrict__ kern,      // 16x16 DCT matrix, row-major fp32
    float* __restrict__ out,
    int strips_per_block, int total_strips)
{
    __shared__ float stage[LDS_FLOATS];

    const int tid  = threadIdx.x;
    const int lane = tid & 63;
    const int wid  = tid >> 6;
    const int li   = lane & 15;          // matrix row index i
    const int g    = lane >> 4;          // k-group 0..3

    // constant fragment: lane holds K[li][4g..4g+3] as bf16 pairs.
    // Serves as B1 (=K^T: B[k][c]=K[c][k], c=li) and A2 (=K: A[i][k], i=li).
    intx2 KF;
    {
        floatx4 kv = *reinterpret_cast<const floatx4*>(kern + li * 16 + 4 * g);
        KF.x = pk2(kv[0], kv[1]);
        KF.y = pk2(kv[2], kv[3]);
    }

    int s0 = blockIdx.x * strips_per_block;
    if (s0 >= total_strips) return;
    int ns = strips_per_block;
    if (s0 + ns > total_strips) ns = total_strips - s0;

    // strip s: 16 rows x 256 cols. band = s>>2, quarter = s&3.
    auto sbase = [](int s) -> size_t {
        return (size_t)(s >> 2) * (16 * IMG_W) + (size_t)(s & 3) * 256;
    };

    // per-tile A1 source: lane reads T[li][t*16 + 4g .. +3], t = 4*wid + tt.
    // One instr = 64 lanes x 16B = the whole 16x16 tile (16 complete 64B lines).
    floatx4 pre[4];
    auto load_strip = [&](int s) {
        const float* gp = x + sbase(s) + (size_t)li * IMG_W + 4 * g;
        #pragma unroll
        for (int tt = 0; tt < 4; ++tt)
            pre[tt] = *reinterpret_cast<const floatx4*>(gp + (4 * wid + tt) * 16);
    };

    load_strip(s0);

    const floatx4 z = {0.f, 0.f, 0.f, 0.f};

    for (int k = 0; k < ns; ++k) {
        // ---- cvt A1 frags (consumes pre), then issue next-strip loads ----
        intx2 A0, A1, A2t, A3;
        A0.x  = pk2(pre[0][0], pre[0][1]);  A0.y  = pk2(pre[0][2], pre[0][3]);
        A1.x  = pk2(pre[1][0], pre[1][1]);  A1.y  = pk2(pre[1][2], pre[1][3]);
        A2t.x = pk2(pre[2][0], pre[2][1]);  A2t.y = pk2(pre[2][2], pre[2][3]);
        A3.x  = pk2(pre[3][0], pre[3][1]);  A3.y  = pk2(pre[3][2], pre[3][3]);
        if (k + 1 < ns) load_strip(s0 + k + 1);   // ~1 full iter of latency slack

        // ---- pass 1: V = T * K^T (4 independent MFMAs) ----
        __builtin_amdgcn_sched_barrier(0);        // keep cvts above (VALU->MFMA gap)
        asm volatile("s_nop 1");
        floatx4 V0, V1, V2, V3;
        MFMA16(V0, A0,  KF, z);
        MFMA16(V1, A1,  KF, z);
        MFMA16(V2, A2t, KF, z);
        MFMA16(V3, A3,  KF, z);
        asm volatile("s_nop 7\n\ts_nop 7");       // MFMA -> VALU-read wait states
        __builtin_amdgcn_sched_barrier(0);        // cvts below may not hoist

        // ---- lane-local transpose: B2[k=4g+j] = V[4g+j] (D1 regs!) ----
        intx2 B0, B1, B2, B3;
        B0.x = pk2(V0[0], V0[1]);  B0.y = pk2(V0[2], V0[3]);
        B1.x = pk2(V1[0], V1[1]);  B1.y = pk2(V1[2], V1[3]);
        B2.x = pk2(V2[0], V2[1]);  B2.y = pk2(V2[2], V2[3]);
        B3.x = pk2(V3[0], V3[1]);  B3.y = pk2(V3[2], V3[3]);

        // ---- pass 2: O = K * V ----
        __builtin_amdgcn_sched_barrier(0);
        asm volatile("s_nop 1");
        floatx4 O0, O1, O2, O3;
        MFMA16(O0, KF, B0, z);
        MFMA16(O1, KF, B1, z);
        MFMA16(O2, KF, B2, z);
        MFMA16(O3, KF, B3, z);
        asm volatile("s_nop 7\n\ts_nop 7");       // MFMA -> LDS-write wait states
        __builtin_amdgcn_sched_barrier(0);

        // ---- stage: O[4g+r][li] -> stage[(4g+r)*SSTR + t*16 + li] ----
        // banks: (16g + 4r + 16t + li) mod 32 -> exactly 2 lanes/bank (free).
        {
            float* st = &stage[(4 * g) * SSTR + (4 * wid) * 16 + li];
            #pragma unroll
            for (int r = 0; r < 4; ++r) {
                st[r * SSTR + 0]  = O0[r];
                st[r * SSTR + 16] = O1[r];
                st[r * SSTR + 32] = O2[r];
                st[r * SSTR + 48] = O3[r];
            }
        }
        asm volatile("s_waitcnt lgkmcnt(0)" ::: "memory");
        __builtin_amdgcn_s_barrier();             // stage complete
        asm volatile("" ::: "memory");

        // ---- tail: read stage rows (1KB, conflict-free b128) and store ----
        {
            const size_t ob = sbase(s0 + k);
            #pragma unroll
            for (int f = 0; f < 4; ++f) {
                const int row = 4 * wid + f;
                floatx4 v = *reinterpret_cast<const floatx4*>(
                    &stage[row * SSTR + lane * 4]);
                *reinterpret_cast<floatx4*>(out + ob + (size_t)row * IMG_W + lane * 4) = v;
            }
        }
        asm volatile("s_waitcnt lgkmcnt(0)" ::: "memory");
        __builtin_amdgcn_s_barrier();             // protect stage for next iter
        asm volatile("" ::: "memory");
    }
}

extern "C" void kernel_launch(void* const* d_in, const int* in_sizes, int n_in,
                              void* d_out, int out_size, void* d_ws, size_t ws_size,
                              hipStream_t stream) {
    const float* x    = (const float*)d_in[0];
    const float* kern = (const float*)d_in[1];
    float* out        = (float*)d_out;

    const int n_img        = in_sizes[0] / (IMG_W * IMG_W);   // 96
    const int total_strips = n_img * 256;                     // 24576 (16x256 strips)
    const int blocks       = 1024;
    const int per_block    = (total_strips + blocks - 1) / blocks;  // 24, exact

    dct16_kernel<<<blocks, 256, 0, stream>>>(x, kern, out, per_block, total_strips);
}

// Round 14
// 166.720 us; speedup vs baseline: 1.1575x; 1.0027x over previous
//
#include <hip/hip_runtime.h>
#include <hip/hip_bf16.h>

// Blockwise 16x16 2D DCT (out = K @ T @ K^T), fp32 in/out, bf16 MFMA compute.
// R14: BARRIER-FREE, LDS-FREE. Each wave independently processes 16x64 jobs
// (4 tiles): 4x b128 loads (16 full 64B lines each) -> cvt -> 4 MFMA ->
// lane-local transpose (D1 regs ARE B2 frags) -> 4 MFMA -> 16x b32 stores,
// where each store instr covers 4 COMPLETE 64B lines (16 lanes x 4B contig).
// 2-job-deep register prefetch. No LDS, no barriers, copy-like issue pattern.
// 2048 blocks x 256 thr = 8192 waves x 12 jobs, exact cover.

#define IMG_W 1024

typedef float floatx4 __attribute__((ext_vector_type(4)));
typedef int   intx2   __attribute__((ext_vector_type(2)));

__device__ __forceinline__ int pk2(float a, float b) {
    __hip_bfloat16 ha = __float2bfloat16(a);
    __hip_bfloat16 hb = __float2bfloat16(b);
    unsigned short ua, ub;
    __builtin_memcpy(&ua, &ha, 2);
    __builtin_memcpy(&ub, &hb, 2);
    return (int)((unsigned)ua | ((unsigned)ub << 16));
}

#define MFMA16(D, A, B, C)                                        \
    asm volatile("v_mfma_f32_16x16x16_bf16 %0, %1, %2, %3"        \
                 : "=&v"(D) : "v"(A), "v"(B), "v"(C))

__global__ __launch_bounds__(256) void dct16_kernel(
    const float* __restrict__ x,
    const float* __restrict__ kern,      // 16x16 DCT matrix, row-major fp32
    float* __restrict__ out,
    int jobs_per_wave, int total_jobs)
{
    const int tid  = threadIdx.x;
    const int lane = tid & 63;
    const int wid  = tid >> 6;
    const int li   = lane & 15;          // matrix row/col index
    const int g    = lane >> 4;          // k-group 0..3

    // constant fragment: lane holds K[li][4g..4g+3] as bf16 pairs.
    // Serves as B1 (=K^T: B[k][c]=K[c][k], c=li) and A2 (=K: A[i][k], i=li).
    intx2 KF;
    {
        floatx4 kv = *reinterpret_cast<const floatx4*>(kern + li * 16 + 4 * g);
        KF.x = pk2(kv[0], kv[1]);
        KF.y = pk2(kv[2], kv[3]);
    }

    const int gw = blockIdx.x * 4 + wid;     // global wave id
    int j0 = gw * jobs_per_wave;
    if (j0 >= total_jobs) return;            // no barriers -> safe
    int nj = jobs_per_wave;
    if (j0 + nj > total_jobs) nj = total_jobs - j0;

    // job j: 16 rows x 64 cols. band = j>>4, col64 = j&15.
    auto jbase = [](int j) -> size_t {
        return (size_t)(j >> 4) * (16 * IMG_W) + (size_t)(j & 15) * 64;
    };

    floatx4 preA[4], preB[4];                // 2-job-deep prefetch
    auto load_job = [&](int j, floatx4 (&pre)[4]) {
        const float* gp = x + jbase(j) + (size_t)li * IMG_W + 4 * g;
        #pragma unroll
        for (int tt = 0; tt < 4; ++tt)       // tile tt: cols 16tt..16tt+15
            pre[tt] = *reinterpret_cast<const floatx4*>(gp + tt * 16);
    };

    const floatx4 z = {0.f, 0.f, 0.f, 0.f};

    auto run_job = [&](floatx4 (&pre)[4], int j, int jpref) {
        // cvt A1 frags (consumes pre; compiler inserts the vmcnt wait here)
        intx2 A0, A1, A2t, A3;
        A0.x  = pk2(pre[0][0], pre[0][1]);  A0.y  = pk2(pre[0][2], pre[0][3]);
        A1.x  = pk2(pre[1][0], pre[1][1]);  A1.y  = pk2(pre[1][2], pre[1][3]);
        A2t.x = pk2(pre[2][0], pre[2][1]);  A2t.y = pk2(pre[2][2], pre[2][3]);
        A3.x  = pk2(pre[3][0], pre[3][1]);  A3.y  = pk2(pre[3][2], pre[3][3]);
        if (jpref >= 0) load_job(jpref, pre);    // refill: 2 jobs of slack

        // pass 1: V = T * K^T
        __builtin_amdgcn_sched_barrier(0);
        asm volatile("s_nop 1");
        floatx4 V0, V1, V2, V3;
        MFMA16(V0, A0,  KF, z);
        MFMA16(V1, A1,  KF, z);
        MFMA16(V2, A2t, KF, z);
        MFMA16(V3, A3,  KF, z);
        asm volatile("s_nop 7\n\ts_nop 7");
        __builtin_amdgcn_sched_barrier(0);

        // lane-local transpose: D1 regs (V rows 4g+r) are B2 elements (k=4g+j)
        intx2 B0, B1, B2, B3;
        B0.x = pk2(V0[0], V0[1]);  B0.y = pk2(V0[2], V0[3]);
        B1.x = pk2(V1[0], V1[1]);  B1.y = pk2(V1[2], V1[3]);
        B2.x = pk2(V2[0], V2[1]);  B2.y = pk2(V2[2], V2[3]);
        B3.x = pk2(V3[0], V3[1]);  B3.y = pk2(V3[2], V3[3]);

        // pass 2: O = K * V
        __builtin_amdgcn_sched_barrier(0);
        asm volatile("s_nop 1");
        floatx4 O0, O1, O2, O3;
        MFMA16(O0, KF, B0, z);
        MFMA16(O1, KF, B1, z);
        MFMA16(O2, KF, B2, z);
        MFMA16(O3, KF, B3, z);
        asm volatile("s_nop 7\n\ts_nop 7");
        __builtin_amdgcn_sched_barrier(0);

        // direct store: instr (r, tt) writes 4 complete 64B lines (one per g):
        // out[base + (4g+r)*W + tt*16 + li], 16 lanes x 4B contiguous per line.
        float* gout = out + jbase(j) + (size_t)(4 * g) * IMG_W + li;
        #pragma unroll
        for (int r = 0; r < 4; ++r) {
            gout[(size_t)r * IMG_W +  0] = O0[r];
            gout[(size_t)r * IMG_W + 16] = O1[r];
            gout[(size_t)r * IMG_W + 32] = O2[r];
            gout[(size_t)r * IMG_W + 48] = O3[r];
        }
    };

    // prologue: 2 jobs in flight
    load_job(j0, preA);
    if (nj > 1) load_job(j0 + 1, preB);

    int k = 0;
    for (; k + 1 < nj; k += 2) {
        run_job(preA, j0 + k,     (k + 2 < nj) ? j0 + k + 2 : -1);
        run_job(preB, j0 + k + 1, (k + 3 < nj) ? j0 + k + 3 : -1);
    }
    if (k < nj) run_job(preA, j0 + k, -1);
}

extern "C" void kernel_launch(void* const* d_in, const int* in_sizes, int n_in,
                              void* d_out, int out_size, void* d_ws, size_t ws_size,
                              hipStream_t stream) {
    const float* x    = (const float*)d_in[0];
    const float* kern = (const float*)d_in[1];
    float* out        = (float*)d_out;

    const int n_img     = in_sizes[0] / (IMG_W * IMG_W);      // 96
    const int total_jobs = n_img * 64 * 16;                   // 98304 jobs of 16x64
    const int blocks    = 2048;                               // 8192 waves
    const int n_waves   = blocks * 4;
    const int per_wave  = (total_jobs + n_waves - 1) / n_waves;   // 12, exact

    dct16_kernel<<<blocks, 256, 0, stream>>>(x, kern, out, per_wave, total_jobs);
}

// Round 15
// 145.999 us; speedup vs baseline: 1.3218x; 1.1419x over previous
//
#include <hip/hip_runtime.h>
#include <hip/hip_bf16.h>

// Blockwise 16x16 2D DCT (out = K @ T @ K^T), fp32 in/out, bf16 MFMA compute.
// R15: COPY-REGIME DISPATCH. Non-persistent: 24576 blocks x 256 thr in address
// order; block b = strip b (4 waves x one 16x64 job). Resident blocks form a
// sliding contiguous ~32MB window over memory (like fill/copy kernels at
// 6.9-7 TB/s) instead of persistent blocks' thousands of scattered streams.
// Per wave (R14's verified math): 4x b128 loads (16 full 64B lines each) ->
// cvt -> 4 MFMA (V = T*K^T) -> lane-local transpose (D1 regs ARE B2 frags) ->
// 4 MFMA (O = K*V) -> 16 stores, each covering 4 complete 64B lines.
// No LDS, no barriers, no loop.

#define IMG_W 1024

typedef float floatx4 __attribute__((ext_vector_type(4)));
typedef int   intx2   __attribute__((ext_vector_type(2)));

__device__ __forceinline__ int pk2(float a, float b) {
    __hip_bfloat16 ha = __float2bfloat16(a);
    __hip_bfloat16 hb = __float2bfloat16(b);
    unsigned short ua, ub;
    __builtin_memcpy(&ua, &ha, 2);
    __builtin_memcpy(&ub, &hb, 2);
    return (int)((unsigned)ua | ((unsigned)ub << 16));
}

#define MFMA16(D, A, B, C)                                        \
    asm volatile("v_mfma_f32_16x16x16_bf16 %0, %1, %2, %3"        \
                 : "=&v"(D) : "v"(A), "v"(B), "v"(C))

__global__ __launch_bounds__(256) void dct16_kernel(
    const float* __restrict__ x,
    const float* __restrict__ kern,      // 16x16 DCT matrix, row-major fp32
    float* __restrict__ out,
    int total_jobs)
{
    const int tid  = threadIdx.x;
    const int lane = tid & 63;
    const int wid  = tid >> 6;
    const int li   = lane & 15;          // matrix row/col index
    const int g    = lane >> 4;          // k-group 0..3

    const int j = blockIdx.x * 4 + wid;  // job id, address order
    if (j >= total_jobs) return;

    // constant fragment: lane holds K[li][4g..4g+3] as bf16 pairs.
    // Serves as B1 (=K^T: B[k][c]=K[c][k], c=li) and A2 (=K: A[i][k], i=li).
    intx2 KF;
    {
        floatx4 kv = *reinterpret_cast<const floatx4*>(kern + li * 16 + 4 * g);
        KF.x = pk2(kv[0], kv[1]);
        KF.y = pk2(kv[2], kv[3]);
    }

    // job j: 16 rows x 64 cols. band = j>>4, col64 = j&15.
    const size_t base = (size_t)(j >> 4) * (16 * IMG_W) + (size_t)(j & 15) * 64;

    // load: tile tt -> lane reads T[li][16tt + 4g .. +3]; one instr = 16 full lines
    const float* gp = x + base + (size_t)li * IMG_W + 4 * g;
    floatx4 pre[4];
    #pragma unroll
    for (int tt = 0; tt < 4; ++tt)
        pre[tt] = *reinterpret_cast<const floatx4*>(gp + tt * 16);

    const floatx4 z = {0.f, 0.f, 0.f, 0.f};

    // cvt A1 frags (vmcnt wait inserted here by compiler)
    intx2 A0, A1, A2t, A3;
    A0.x  = pk2(pre[0][0], pre[0][1]);  A0.y  = pk2(pre[0][2], pre[0][3]);
    A1.x  = pk2(pre[1][0], pre[1][1]);  A1.y  = pk2(pre[1][2], pre[1][3]);
    A2t.x = pk2(pre[2][0], pre[2][1]);  A2t.y = pk2(pre[2][2], pre[2][3]);
    A3.x  = pk2(pre[3][0], pre[3][1]);  A3.y  = pk2(pre[3][2], pre[3][3]);

    // pass 1: V = T * K^T
    __builtin_amdgcn_sched_barrier(0);
    asm volatile("s_nop 1");
    floatx4 V0, V1, V2, V3;
    MFMA16(V0, A0,  KF, z);
    MFMA16(V1, A1,  KF, z);
    MFMA16(V2, A2t, KF, z);
    MFMA16(V3, A3,  KF, z);
    asm volatile("s_nop 7\n\ts_nop 7");
    __builtin_amdgcn_sched_barrier(0);

    // lane-local transpose: D1 regs (V rows 4g+r) are B2 elements (k=4g+j)
    intx2 B0, B1, B2, B3;
    B0.x = pk2(V0[0], V0[1]);  B0.y = pk2(V0[2], V0[3]);
    B1.x = pk2(V1[0], V1[1]);  B1.y = pk2(V1[2], V1[3]);
    B2.x = pk2(V2[0], V2[1]);  B2.y = pk2(V2[2], V2[3]);
    B3.x = pk2(V3[0], V3[1]);  B3.y = pk2(V3[2], V3[3]);

    // pass 2: O = K * V
    __builtin_amdgcn_sched_barrier(0);
    asm volatile("s_nop 1");
    floatx4 O0, O1, O2, O3;
    MFMA16(O0, KF, B0, z);
    MFMA16(O1, KF, B1, z);
    MFMA16(O2, KF, B2, z);
    MFMA16(O3, KF, B3, z);
    asm volatile("s_nop 7\n\ts_nop 7");
    __builtin_amdgcn_sched_barrier(0);

    // store: instr (r, tt) writes 4 complete 64B lines (one per g):
    // out[base + (4g+r)*W + tt*16 + li], 16 lanes x 4B contiguous per line.
    float* gout = out + base + (size_t)(4 * g) * IMG_W + li;
    #pragma unroll
    for (int r = 0; r < 4; ++r) {
        gout[(size_t)r * IMG_W +  0] = O0[r];
        gout[(size_t)r * IMG_W + 16] = O1[r];
        gout[(size_t)r * IMG_W + 32] = O2[r];
        gout[(size_t)r * IMG_W + 48] = O3[r];
    }
}

extern "C" void kernel_launch(void* const* d_in, const int* in_sizes, int n_in,
                              void* d_out, int out_size, void* d_ws, size_t ws_size,
                              hipStream_t stream) {
    const float* x    = (const float*)d_in[0];
    const float* kern = (const float*)d_in[1];
    float* out        = (float*)d_out;

    const int n_img      = in_sizes[0] / (IMG_W * IMG_W);     // 96
    const int total_jobs = n_img * 64 * 16;                   // 98304 jobs of 16x64
    const int blocks     = (total_jobs + 3) / 4;              // 24576, address order

    dct16_kernel<<<blocks, 256, 0, stream>>>(x, kern, out, total_jobs);
}